// Round 10
// baseline (172.111 us; speedup 1.0000x reference)
//
#include <hip/hip_runtime.h>
#include <hip/hip_bf16.h>
#include <stdint.h>

#define NB    4096
#define NROWS 8192
#define DIM   512
#define BM    128
#define TK    128                     // K per MX-fp8 MFMA tile
#define NBLK  2176                    // 8 XCDs x 272 (96 early-exit)

typedef __attribute__((ext_vector_type(4))) float f32x4;
typedef __attribute__((ext_vector_type(4))) int   i32x4;
typedef __attribute__((ext_vector_type(8))) int   i32x8;

#define SCALE_E8M0 0x7B7B7B7Bu   // 2^-4 per 32-elem block, all blocks

// f32 -> OCP e4m3fn, RNE. Inputs |x| <= ~8 here (no sat needed).
__device__ __forceinline__ unsigned char f2e4m3(float x) {
  uint32_t u = __float_as_uint(x);
  uint32_t s = (u >> 24) & 0x80u;
  uint32_t e = (u >> 23) & 0xffu;
  if (e < 117u) return (unsigned char)s;          // < 2^-10 -> 0
  if (e >= 121u) {                                // normal fp8 range
    u += 0x7FFFFu + ((u >> 20) & 1u);             // RNE on mantissa bit 20
    e = (u >> 23) & 0xffu;
    uint32_t m = (u >> 20) & 7u;
    return (unsigned char)(s | ((e - 120u) << 3) | m);
  }
  float af = __uint_as_float(u & 0x7fffffffu);    // subnormal: step 2^-9
  int q = (int)(af * 512.0f + 0.5f);
  return (unsigned char)(q > 7 ? (s | 0x08u) : (s | (uint32_t)q));
}

__device__ __forceinline__ void gload_lds16(const void* g, void* l) {
  __builtin_amdgcn_global_load_lds(
      (const __attribute__((address_space(1))) void*)g,
      (__attribute__((address_space(3))) void*)l, 16, 0, 0);
}

__device__ __forceinline__ i32x8 ld_frag(const char* base, int o0, int o1) {
  i32x4 lo = *(const i32x4*)(base + o0);
  i32x4 hi = *(const i32x4*)(base + o1);
  i32x8 r = {lo[0], lo[1], lo[2], lo[3], hi[0], hi[1], hi[2], hi[3]};
  return r;
}

// ---- Kernel 1: normalize rows -> fp8 P (v*16, e4m3), pos partials, zero ---
__global__ __launch_bounds__(256) void normalize_pos_kernel(
    const float* __restrict__ zi, const float* __restrict__ zj,
    unsigned char* __restrict__ p, float* __restrict__ rowsum,
    float* __restrict__ posp) {
  __shared__ float ws4[4];
  const int wave = threadIdx.x >> 6;
  const int lane = threadIdx.x & 63;
  const int i    = blockIdx.x * 4 + wave;          // 0..4095

  int gt = blockIdx.x * 256 + threadIdx.x;
  if (gt < NROWS) rowsum[gt] = 0.f;

  const float4* sa = (const float4*)(zi + (size_t)i * DIM);
  const float4* sb = (const float4*)(zj + (size_t)i * DIM);
  float4 a0 = sa[lane * 2], a1 = sa[lane * 2 + 1];
  float4 b0 = sb[lane * 2], b1 = sb[lane * 2 + 1];
  float va[8] = {a0.x, a0.y, a0.z, a0.w, a1.x, a1.y, a1.z, a1.w};
  float vb[8] = {b0.x, b0.y, b0.z, b0.w, b1.x, b1.y, b1.z, b1.w};
  float ssa = 0.f, ssb = 0.f;
#pragma unroll
  for (int j = 0; j < 8; ++j) { ssa += va[j] * va[j]; ssb += vb[j] * vb[j]; }
#pragma unroll
  for (int off = 32; off; off >>= 1) {
    ssa += __shfl_xor(ssa, off);
    ssb += __shfl_xor(ssb, off);
  }
  float inva = rsqrtf(ssa), invb = rsqrtf(ssb);

  union { unsigned char b[8]; uint2 v; } qa, qb;
  float d = 0.f;
#pragma unroll
  for (int j = 0; j < 8; ++j) {
    float na = va[j] * inva, nb = vb[j] * invb;
    qa.b[j] = f2e4m3(na * 16.0f);
    qb.b[j] = f2e4m3(nb * 16.0f);
    d += na * nb;
  }
  *(uint2*)(p + (size_t)i * DIM + lane * 8)        = qa.v;
  *(uint2*)(p + (size_t)(i + NB) * DIM + lane * 8) = qb.v;

#pragma unroll
  for (int off = 32; off; off >>= 1) d += __shfl_xor(d, off);
  if (lane == 0) ws4[wave] = d;
  __syncthreads();
  if (threadIdx.x == 0)
    posp[blockIdx.x] = 4.0f * (ws4[0] + ws4[1] + ws4[2] + ws4[3]);
}

// ---- Kernel 2: symmetric fused S = 2*P*P^T (MX-fp8) -> exp -> row+col sums
// All 4 K-tiles get their OWN LDS buffer (128 KB total, nothing overwritten):
// only 4 barriers per block, counted vmcnt (never 0 until last tile), tiles
// staged 2-3 phases ahead. 512 threads = 8 waves (2m x 4n), per-wave 64x32.
// Swizzle + fragment layout identical to R8 (verified): LDS rows 128 B,
// 8 chunks of 16 B, chunk ^= (row&7); pre-swizzled global source.
__global__ __launch_bounds__(512, 1) void simexp_kernel(
    const unsigned char* __restrict__ p, float* __restrict__ rowsum) {
  __shared__ __align__(16) unsigned char As[4][BM * TK];   // 4 x 16 KB
  __shared__ __align__(16) unsigned char Bs[4][BM * TK];   // 4 x 16 KB

  const int x = blockIdx.x & 7;          // XCD (round-robin heuristic)
  const int l = blockIdx.x >> 3;         // 0..271 local index
  int bi, bj;
  if (x < 6) {
    if (l >= 256) return;                // uniform early-exit, before barriers
    const int sqi[6] = {0, 0, 0, 1, 1, 2};
    const int sqj[6] = {1, 2, 3, 2, 3, 3};
    bi = sqi[x] * 16 + (l >> 4);
    bj = sqj[x] * 16 + (l & 15);
  } else {
    int s  = (x == 6) ? 0 : 2;
    int ll = l;
    if (ll >= 136) { ll -= 136; s += 1; }
    int i = 0;
    while ((i + 1) * (33 - (i + 1)) / 2 <= ll) ++i;
    int j = i + (ll - i * (33 - i) / 2);
    bi = s * 16 + i;
    bj = s * 16 + j;
  }
  const bool diag = (bi == bj);

  const int tid  = threadIdx.x;
  const int wave = tid >> 6;       // 0..7
  const int lane = tid & 63;
  const int wm   = wave >> 2;      // 0..1 : 64-row half
  const int wn   = wave & 3;       // 0..3 : 32-col quarter
  const int frow = lane & 15;
  const int kc   = lane >> 4;      // 0..3 : 32-elem k-block

  const unsigned char* pa = p + (size_t)(bi * BM) * DIM;
  const unsigned char* pb = p + (size_t)(bj * BM) * DIM;

  // staging: per issue a wave covers 8 rows x 128B; lane -> (row8, chunk)
  const int row8 = lane >> 3;                // 0..7
  const int gch  = (lane & 7) ^ row8;        // pre-swizzled 16B chunk

#define STAGE(t)                                                              \
  {                                                                           \
    _Pragma("unroll")                                                         \
    for (int i = 0; i < 2; ++i) {                                             \
      int rbase = i * 64 + wave * 8;                                          \
      gload_lds16(pa + (size_t)(rbase + row8) * DIM + (t) * TK + gch * 16,    \
                  (char*)As[t] + rbase * 128);                                \
      gload_lds16(pb + (size_t)(rbase + row8) * DIM + (t) * TK + gch * 16,    \
                  (char*)Bs[t] + rbase * 128);                                \
    }                                                                         \
  }

  // ds_read byte offsets (rows are 0 mod 8 at frag base -> row&7 == frow&7)
  int offA[4][2], offB[2][2];
#pragma unroll
  for (int m = 0; m < 4; ++m)
#pragma unroll
    for (int j = 0; j < 2; ++j)
      offA[m][j] = (wm * 64 + m * 16 + frow) * 128 +
                   ((kc * 2 + j) ^ (frow & 7)) * 16;
#pragma unroll
  for (int n = 0; n < 2; ++n)
#pragma unroll
    for (int j = 0; j < 2; ++j)
      offB[n][j] = (wn * 32 + n * 16 + frow) * 128 +
                   ((kc * 2 + j) ^ (frow & 7)) * 16;

  f32x4 acc[4][2] = {};

#define COMPUTE(t)                                                            \
  {                                                                           \
    i32x8 af[4], bfr[2];                                                      \
    _Pragma("unroll")                                                         \
    for (int m = 0; m < 4; ++m)                                               \
      af[m] = ld_frag((const char*)As[t], offA[m][0], offA[m][1]);            \
    _Pragma("unroll")                                                         \
    for (int n = 0; n < 2; ++n)                                               \
      bfr[n] = ld_frag((const char*)Bs[t], offB[n][0], offB[n][1]);           \
    __builtin_amdgcn_s_setprio(1);                                            \
    _Pragma("unroll")                                                         \
    for (int m = 0; m < 4; ++m)                                               \
      _Pragma("unroll")                                                       \
      for (int n = 0; n < 2; ++n)                                             \
        acc[m][n] = __builtin_amdgcn_mfma_scale_f32_16x16x128_f8f6f4(         \
            af[m], bfr[n], acc[m][n], 0, 0, 0, SCALE_E8M0, 0, SCALE_E8M0);    \
    __builtin_amdgcn_s_setprio(0);                                            \
  }

  STAGE(0); STAGE(1); STAGE(2);                       // 12 loads in flight
  asm volatile("s_waitcnt vmcnt(8)" ::: "memory");    // tile 0 landed
  __builtin_amdgcn_s_barrier();
  STAGE(3);                                           // issue last tile early
  COMPUTE(0);
  asm volatile("s_waitcnt vmcnt(8)" ::: "memory");    // tile 1 landed
  __builtin_amdgcn_s_barrier();
  COMPUTE(1);
  asm volatile("s_waitcnt vmcnt(4)" ::: "memory");    // tile 2 landed
  __builtin_amdgcn_s_barrier();
  COMPUTE(2);
  asm volatile("s_waitcnt vmcnt(0)" ::: "memory");    // tile 3 landed
  __builtin_amdgcn_s_barrier();
  COMPUTE(3);

  // epilogue: e = exp(2s); rowsum[row] += e; rowsum[col] += e if off-diag
  const int r4 = lane >> 4;   // C/D: col = lane&15, row = (lane>>4)*4 + reg
  const int cl = lane & 15;

  float rowpart[4][4];
  float colpart[2] = {0.f, 0.f};

  if (diag) {
#pragma unroll
    for (int m = 0; m < 4; ++m)
#pragma unroll
      for (int r = 0; r < 4; ++r) {
        int grow = bi * BM + wm * 64 + m * 16 + r4 * 4 + r;
        float s = 0.f;
#pragma unroll
        for (int n = 0; n < 2; ++n) {
          int gcol = bj * BM + wn * 32 + n * 16 + cl;
          float e  = __expf(2.0f * acc[m][n][r]);
          s += (grow == gcol) ? 0.f : e;
        }
        rowpart[m][r] = s;
      }
  } else {
#pragma unroll
    for (int m = 0; m < 4; ++m)
#pragma unroll
      for (int r = 0; r < 4; ++r) {
        float s = 0.f;
#pragma unroll
        for (int n = 0; n < 2; ++n) {
          float e = __expf(2.0f * acc[m][n][r]);
          s += e;
          colpart[n] += e;
        }
        rowpart[m][r] = s;
      }
  }

#pragma unroll
  for (int m = 0; m < 4; ++m)
#pragma unroll
    for (int r = 0; r < 4; ++r) {
      float s = rowpart[m][r];
      s += __shfl_xor(s, 1);
      s += __shfl_xor(s, 2);
      s += __shfl_xor(s, 4);
      s += __shfl_xor(s, 8);
      if (cl == 0) {
        int grow = bi * BM + wm * 64 + m * 16 + r4 * 4 + r;
        atomicAdd(&rowsum[grow], s);
      }
    }

  if (!diag) {
#pragma unroll
    for (int n = 0; n < 2; ++n) {
      float c = colpart[n];
      c += __shfl_xor(c, 16);
      c += __shfl_xor(c, 32);
      if (r4 == 0) {
        int gcol = bj * BM + wn * 32 + n * 16 + cl;
        atomicAdd(&rowsum[gcol], c);
      }
    }
  }
}

// ---- Kernel 3: finalize loss ---------------------------------------------
__global__ __launch_bounds__(256) void finalize_kernel(
    const float* __restrict__ rowsum, const float* __restrict__ posp,
    float* __restrict__ out) {
  __shared__ float ws4[4];
  int tid = threadIdx.x;
  float v = 0.f;
  for (int i = tid; i < NROWS; i += 256) v += logf(rowsum[i]);
  for (int i = tid; i < 1024; i += 256) v -= posp[i];
#pragma unroll
  for (int off = 32; off; off >>= 1) v += __shfl_xor(v, off);
  if ((tid & 63) == 0) ws4[tid >> 6] = v;
  __syncthreads();
  if (tid == 0)
    out[0] = (ws4[0] + ws4[1] + ws4[2] + ws4[3]) / (float)NROWS;
}

extern "C" void kernel_launch(void* const* d_in, const int* in_sizes, int n_in,
                              void* d_out, int out_size, void* d_ws,
                              size_t ws_size, hipStream_t stream) {
  const float* zi = (const float*)d_in[0];
  const float* zj = (const float*)d_in[1];
  float* out      = (float*)d_out;

  char* ws          = (char*)d_ws;
  unsigned char* p  = (unsigned char*)ws;                        // 4 MB fp8
  float* rowsum     = (float*)(ws + (size_t)NROWS * DIM);        // 32 KB
  float* posp       = rowsum + NROWS;                            // 4 KB

  normalize_pos_kernel<<<NB / 4, 256, 0, stream>>>(zi, zj, p, rowsum, posp);
  simexp_kernel<<<NBLK, 512, 0, stream>>>(p, rowsum);
  finalize_kernel<<<1, 256, 0, stream>>>(rowsum, posp, out);
}

// Round 11
// 65.767 us; speedup vs baseline: 2.6170x; 2.6170x over previous
//
#include <hip/hip_runtime.h>
#include <hip/hip_bf16.h>
#include <stdint.h>

#define NB    4096
#define NROWS 8192
#define DIM   512
#define BM    128
#define TK    128                     // K per MX-fp8 MFMA tile
#define NKT   4                       // K-tiles per output tile
#define SBLK  512                     // simexp grid: 2 blocks/CU, persistent

typedef __attribute__((ext_vector_type(4))) float f32x4;
typedef __attribute__((ext_vector_type(4))) int   i32x4;
typedef __attribute__((ext_vector_type(8))) int   i32x8;

#define SCALE_E8M0 0x7B7B7B7Bu   // 2^-4 per 32-elem block, all blocks

// f32 -> OCP e4m3fn, RNE. Inputs |x| <= ~8 here (no sat needed).
__device__ __forceinline__ unsigned char f2e4m3(float x) {
  uint32_t u = __float_as_uint(x);
  uint32_t s = (u >> 24) & 0x80u;
  uint32_t e = (u >> 23) & 0xffu;
  if (e < 117u) return (unsigned char)s;          // < 2^-10 -> 0
  if (e >= 121u) {                                // normal fp8 range
    u += 0x7FFFFu + ((u >> 20) & 1u);             // RNE on mantissa bit 20
    e = (u >> 23) & 0xffu;
    uint32_t m = (u >> 20) & 7u;
    return (unsigned char)(s | ((e - 120u) << 3) | m);
  }
  float af = __uint_as_float(u & 0x7fffffffu);    // subnormal: step 2^-9
  int q = (int)(af * 512.0f + 0.5f);
  return (unsigned char)(q > 7 ? (s | 0x08u) : (s | (uint32_t)q));
}

__device__ __forceinline__ void gload_lds16(const void* g, void* l) {
  __builtin_amdgcn_global_load_lds(
      (const __attribute__((address_space(1))) void*)g,
      (__attribute__((address_space(3))) void*)l, 16, 0, 0);
}

__device__ __forceinline__ i32x8 ld_frag(const char* base, int o0, int o1) {
  i32x4 lo = *(const i32x4*)(base + o0);
  i32x4 hi = *(const i32x4*)(base + o1);
  i32x8 r = {lo[0], lo[1], lo[2], lo[3], hi[0], hi[1], hi[2], hi[3]};
  return r;
}

// ---- Kernel 1: normalize -> fp8 P (v*16), pos partials; 256 blocks x4 -----
__global__ __launch_bounds__(256) void normalize_pos_kernel(
    const float* __restrict__ zi, const float* __restrict__ zj,
    unsigned char* __restrict__ p, float* __restrict__ rowsum,
    float* __restrict__ posp) {
  __shared__ float ws4[4];
  const int wave = threadIdx.x >> 6;
  const int lane = threadIdx.x & 63;

  int gt = blockIdx.x * 256 + threadIdx.x;
  if (gt < NROWS) rowsum[gt] = 0.f;

  float dtot = 0.f;
#pragma unroll
  for (int it = 0; it < 4; ++it) {
    const int i = blockIdx.x * 4 + wave + it * 1024;   // 0..4095
    const float4* sa = (const float4*)(zi + (size_t)i * DIM);
    const float4* sb = (const float4*)(zj + (size_t)i * DIM);
    float4 a0 = sa[lane * 2], a1 = sa[lane * 2 + 1];
    float4 b0 = sb[lane * 2], b1 = sb[lane * 2 + 1];
    float va[8] = {a0.x, a0.y, a0.z, a0.w, a1.x, a1.y, a1.z, a1.w};
    float vb[8] = {b0.x, b0.y, b0.z, b0.w, b1.x, b1.y, b1.z, b1.w};
    float ssa = 0.f, ssb = 0.f;
#pragma unroll
    for (int j = 0; j < 8; ++j) { ssa += va[j] * va[j]; ssb += vb[j] * vb[j]; }
#pragma unroll
    for (int off = 32; off; off >>= 1) {
      ssa += __shfl_xor(ssa, off);
      ssb += __shfl_xor(ssb, off);
    }
    float inva = rsqrtf(ssa), invb = rsqrtf(ssb);
    union { unsigned char b[8]; uint2 v; } qa, qb;
#pragma unroll
    for (int j = 0; j < 8; ++j) {
      float na = va[j] * inva, nb = vb[j] * invb;
      qa.b[j] = f2e4m3(na * 16.0f);
      qb.b[j] = f2e4m3(nb * 16.0f);
      dtot += na * nb;
    }
    *(uint2*)(p + (size_t)i * DIM + lane * 8)        = qa.v;
    *(uint2*)(p + (size_t)(i + NB) * DIM + lane * 8) = qb.v;
  }

#pragma unroll
  for (int off = 32; off; off >>= 1) dtot += __shfl_xor(dtot, off);
  if (lane == 0) ws4[wave] = dtot;
  __syncthreads();
  if (threadIdx.x == 0)
    posp[blockIdx.x] = 4.0f * (ws4[0] + ws4[1] + ws4[2] + ws4[3]);
}

// decode (xcd x, local slot l) -> tile (bi,bj); supertile partition (R3/R6):
__device__ __forceinline__ void decode_tile(int x, int l, int* pbi, int* pbj) {
  if (x < 6) {
    const int sqi[6] = {0, 0, 0, 1, 1, 2};
    const int sqj[6] = {1, 2, 3, 2, 3, 3};
    *pbi = sqi[x] * 16 + (l >> 4);
    *pbj = sqj[x] * 16 + (l & 15);
  } else {
    int s  = (x == 6) ? 0 : 2;
    int ll = l;
    if (ll >= 136) { ll -= 136; s += 1; }
    int i = 0;
    while ((i + 1) * (33 - (i + 1)) / 2 <= ll) ++i;
    int j = i + (ll - i * (33 - i) / 2);
    *pbi = s * 16 + i;
    *pbj = s * 16 + j;
  }
}

// ---- Kernel 2: symmetric fused S = 2*P*P^T (MX-fp8) -> exp -> row+col sums
// 512 persistent blocks (2/CU, one dispatch generation). Block b serves XCD
// b&7 with 4-5 consecutive tiles of its supertile list (A-panel L1 reuse).
// Flattened (tile,ktile) pipeline, ping-pong 2x32KB LDS, counted vmcnt(8).
// Inner STAGE/fragment/swizzle/epilogue identical to R8 (verified, 0 confl).
__global__ __launch_bounds__(256, 2) void simexp_kernel(
    const unsigned char* __restrict__ p, float* __restrict__ rowsum) {
  __shared__ __align__(16) unsigned char As2[2][BM * TK];   // 2 x 16 KB
  __shared__ __align__(16) unsigned char Bs2[2][BM * TK];   // 2 x 16 KB

  const int x  = blockIdx.x & 7;         // XCD
  const int lb = blockIdx.x >> 3;        // 0..63 local block
  int start, cnt;
  if (x < 6) { start = lb * 4; cnt = 4; }                       // 256 tiles
  else if (lb < 48) { start = lb * 4; cnt = 4; }                // 272 tiles
  else { start = 192 + (lb - 48) * 5; cnt = 5; }

  const int tid  = threadIdx.x;
  const int wave = tid >> 6;
  const int lane = tid & 63;
  const int wm   = wave >> 1;
  const int wn   = wave & 1;
  const int frow = lane & 15;
  const int kc   = lane >> 4;            // 0..3 : 32-elem k-block

  const int row8 = lane >> 3;            // 0..7
  const int gch  = (lane & 7) ^ row8;    // pre-swizzled 16B chunk

#define STAGE(bi_, bj_, t_, buf_)                                             \
  {                                                                           \
    const unsigned char* pa_ = p + (size_t)((bi_)*BM) * DIM;                  \
    const unsigned char* pb_ = p + (size_t)((bj_)*BM) * DIM;                  \
    _Pragma("unroll")                                                         \
    for (int q = 0; q < 4; ++q) {                                             \
      int rbase = q * 32 + wave * 8;                                          \
      gload_lds16(pa_ + (size_t)(rbase + row8) * DIM + (t_)*TK + gch * 16,    \
                  (char*)As2[buf_] + rbase * 128);                            \
      gload_lds16(pb_ + (size_t)(rbase + row8) * DIM + (t_)*TK + gch * 16,    \
                  (char*)Bs2[buf_] + rbase * 128);                            \
    }                                                                         \
  }

  // ds_read byte offsets (verified R8): row*128 + ((kc*2+j)^(row&7))*16
  int offA[4][2], offB[4][2];
#pragma unroll
  for (int m = 0; m < 4; ++m) {
    int row = wm * 64 + m * 16 + frow;
#pragma unroll
    for (int j = 0; j < 2; ++j)
      offA[m][j] = row * 128 + ((kc * 2 + j) ^ (row & 7)) * 16;
  }
#pragma unroll
  for (int n = 0; n < 4; ++n) {
    int row = wn * 64 + n * 16 + frow;
#pragma unroll
    for (int j = 0; j < 2; ++j)
      offB[n][j] = row * 128 + ((kc * 2 + j) ^ (row & 7)) * 16;
  }

  const int r4 = lane >> 4;   // C/D: col = lane&15, row = (lane>>4)*4 + reg
  const int cl = lane & 15;

  int cbi, cbj;
  decode_tile(x, start, &cbi, &cbj);
  STAGE(cbi, cbj, 0, 0);

  const int W = cnt * 4;
  int w = 0;

  for (int tt = 0; tt < cnt; ++tt) {
    int nbi = cbi, nbj = cbj;
    if (tt + 1 < cnt) decode_tile(x, start + tt + 1, &nbi, &nbj);

    f32x4 acc[4][4] = {};

#pragma unroll
    for (int t = 0; t < NKT; ++t) {
      const int nw = w + 1;
      if (nw < W) {
        if (t < NKT - 1) { STAGE(cbi, cbj, t + 1, nw & 1); }
        else             { STAGE(nbi, nbj, 0,     nw & 1); }
        asm volatile("s_waitcnt vmcnt(8)" ::: "memory");   // item w landed
      } else {
        asm volatile("s_waitcnt vmcnt(0)" ::: "memory");
      }
      __builtin_amdgcn_s_barrier();
      {
        const char* Ab = (const char*)As2[w & 1];
        const char* Bb = (const char*)Bs2[w & 1];
        i32x8 af[4], bfr[4];
#pragma unroll
        for (int m = 0; m < 4; ++m) af[m] = ld_frag(Ab, offA[m][0], offA[m][1]);
#pragma unroll
        for (int n = 0; n < 4; ++n) bfr[n] = ld_frag(Bb, offB[n][0], offB[n][1]);
#pragma unroll
        for (int m = 0; m < 4; ++m)
#pragma unroll
          for (int n = 0; n < 4; ++n)
            acc[m][n] = __builtin_amdgcn_mfma_scale_f32_16x16x128_f8f6f4(
                af[m], bfr[n], acc[m][n], 0, 0, 0, SCALE_E8M0, 0, SCALE_E8M0);
      }
      __builtin_amdgcn_s_barrier();   // reads done -> next STAGE may overwrite
      ++w;
    }

    // ---- epilogue for tile (cbi,cbj) (R8-verified) ----
    const bool diag = (cbi == cbj);
    float rowpart[4][4];
    float colpart[4] = {0.f, 0.f, 0.f, 0.f};

    if (diag) {
#pragma unroll
      for (int m = 0; m < 4; ++m)
#pragma unroll
        for (int r = 0; r < 4; ++r) {
          int grow = cbi * BM + wm * 64 + m * 16 + r4 * 4 + r;
          float s = 0.f;
#pragma unroll
          for (int n = 0; n < 4; ++n) {
            int gcol = cbj * BM + wn * 64 + n * 16 + cl;
            float e  = __expf(2.0f * acc[m][n][r]);
            s += (grow == gcol) ? 0.f : e;
          }
          rowpart[m][r] = s;
        }
    } else {
#pragma unroll
      for (int m = 0; m < 4; ++m)
#pragma unroll
        for (int r = 0; r < 4; ++r) {
          float s = 0.f;
#pragma unroll
          for (int n = 0; n < 4; ++n) {
            float e = __expf(2.0f * acc[m][n][r]);
            s += e;
            colpart[n] += e;
          }
          rowpart[m][r] = s;
        }
    }

#pragma unroll
    for (int m = 0; m < 4; ++m)
#pragma unroll
      for (int r = 0; r < 4; ++r) {
        float s = rowpart[m][r];
        s += __shfl_xor(s, 1);
        s += __shfl_xor(s, 2);
        s += __shfl_xor(s, 4);
        s += __shfl_xor(s, 8);
        if (cl == 0) {
          int grow = cbi * BM + wm * 64 + m * 16 + r4 * 4 + r;
          atomicAdd(&rowsum[grow], s);
        }
      }

    if (!diag) {
#pragma unroll
      for (int n = 0; n < 4; ++n) {
        float c = colpart[n];
        c += __shfl_xor(c, 16);
        c += __shfl_xor(c, 32);
        if (r4 == 0) {
          int gcol = cbj * BM + wn * 64 + n * 16 + cl;
          atomicAdd(&rowsum[gcol], c);
        }
      }
    }

    cbi = nbi; cbj = nbj;
  }
}

// ---- Kernel 3: finalize loss ---------------------------------------------
__global__ __launch_bounds__(256) void finalize_kernel(
    const float* __restrict__ rowsum, const float* __restrict__ posp,
    float* __restrict__ out) {
  __shared__ float ws4[4];
  int tid = threadIdx.x;
  float v = 0.f;
  for (int i = tid; i < NROWS; i += 256) v += logf(rowsum[i]);
  if (tid < 256) v -= posp[tid];
#pragma unroll
  for (int off = 32; off; off >>= 1) v += __shfl_xor(v, off);
  if ((tid & 63) == 0) ws4[tid >> 6] = v;
  __syncthreads();
  if (tid == 0)
    out[0] = (ws4[0] + ws4[1] + ws4[2] + ws4[3]) / (float)NROWS;
}

extern "C" void kernel_launch(void* const* d_in, const int* in_sizes, int n_in,
                              void* d_out, int out_size, void* d_ws,
                              size_t ws_size, hipStream_t stream) {
  const float* zi = (const float*)d_in[0];
  const float* zj = (const float*)d_in[1];
  float* out      = (float*)d_out;

  char* ws          = (char*)d_ws;
  unsigned char* p  = (unsigned char*)ws;                        // 4 MB fp8
  float* rowsum     = (float*)(ws + (size_t)NROWS * DIM);        // 32 KB
  float* posp       = rowsum + NROWS;                            // 1 KB

  normalize_pos_kernel<<<256, 256, 0, stream>>>(zi, zj, p, rowsum, posp);
  simexp_kernel<<<SBLK, 256, 0, stream>>>(p, rowsum);
  finalize_kernel<<<1, 256, 0, stream>>>(rowsum, posp, out);
}